// Round 9
// baseline (608.355 us; speedup 1.0000x reference)
//
#include <hip/hip_runtime.h>

// AttentionHead: B=16384, W=10, D=1024, K=V=64
// out[b,i,:] = softmax_j( min(k_i . q_j, tri) ) @ v    (scores row = key index)
//
// GEMM front-end: 6-term split-bf16 MFMA (x,w in 3 bf16 pieces; products
// hh,hm,mh,hl,mm,lh) -> fp32-grade projections; f64 attention epilogue;
// FLOAT32 output.
//
// Round-9 structure: NO LDS in the K-loop. A-fragments are loaded straight
// from row-major x (8 contiguous f32 per lane = exactly one MFMA fragment)
// and split to bf16 pieces in registers; W fragments stream from L2.
// Zero barriers / zero ds_read in the GEMM -> waves drift freely.
// LDS = epilogue only (two-phase kq->v overlay, 49.6 KB) -> 3 blocks/CU.

#define D 1024
#define BM 80            // 8 batches of 10 rows per block
#define KCHUNKS 16       // 1024 / 64
#define KQSTR 133        // kq row stride (floats), odd -> conflict-free-ish
#define VSTR 65          // v row stride (floats)

typedef __attribute__((ext_vector_type(8))) short bf16x8;
typedef __attribute__((ext_vector_type(4))) float f32x4;

static __device__ __forceinline__ unsigned short f2bf_rtne(float f) {
    unsigned int u = __builtin_bit_cast(unsigned int, f);
    u += 0x7fffu + ((u >> 16) & 1u);
    return (unsigned short)(u >> 16);
}
static __device__ __forceinline__ float bf2f(unsigned short h) {
    unsigned int u = ((unsigned int)h) << 16;
    return __builtin_bit_cast(float, u);
}

// --- kernel0: split wk|wq|wv into transposed bf16 3-piece Wt[n][k]
__global__ __launch_bounds__(256) void prep_w(const float* __restrict__ wk,
                                              const float* __restrict__ wq,
                                              const float* __restrict__ wv,
                                              unsigned short* __restrict__ wth,
                                              unsigned short* __restrict__ wtm,
                                              unsigned short* __restrict__ wtl) {
    int idx = blockIdx.x * 256 + threadIdx.x;   // idx = n*1024 + kk, n in [0,192)
    int n  = idx >> 10;
    int kk = idx & 1023;
    const float* src = (n < 64) ? wk : (n < 128) ? wq : wv;
    float w = src[kk * 64 + (n & 63)];
    unsigned short h = f2bf_rtne(w);
    float r1 = w - bf2f(h);                     // exact
    unsigned short m = f2bf_rtne(r1);
    float r2 = r1 - bf2f(m);                    // exact
    wth[idx] = h;
    wtm[idx] = m;
    wtl[idx] = f2bf_rtne(r2);
}

// --- kernel1: fused 6-term projection GEMM (register-direct A) + f64 attention
__global__ __launch_bounds__(256, 3) void fused_attn(
        const float* __restrict__ x,
        const unsigned short* __restrict__ wth,
        const unsigned short* __restrict__ wtm,
        const unsigned short* __restrict__ wtl,
        float* __restrict__ out) {

    __shared__ char smem[49600];
    float*  kq  = (float*)smem;                  // [80][KQSTR] = 42560 B
    float*  vv  = (float*)smem;                  // [80][VSTR] overlay (phase 3+)
    double* scd = (double*)(smem + 42560);       // 4 waves x 2 bb x 110 f64

    const int tid  = threadIdx.x;
    const int wave = tid >> 6;
    const int lane = tid & 63;
    const int m0   = blockIdx.x * BM;
    const int nbase = wave * 48;          // 3 n-tiles of 16 per wave (192 total)
    const int arow  = lane & 15;
    const int apart = lane >> 4;          // 0..3

    // ---------- layout probe (register-only): acc (lane,reg) -> (row, col) ----
    bf16x8 aprobe = {}, bone = {}, aone = {}, bcol = {};
    if (apart == 0) {
        aprobe[0] = (short)f2bf_rtne((float)(arow + 1));  // A[m][0] = m+1
        bone[0]   = (short)0x3F80;                        // B[0][n] = 1
        aone[0]   = (short)0x3F80;                        // A[m][0] = 1
        bcol[0]   = (short)f2bf_rtne((float)(arow + 1));  // B[0][n] = n+1
    }
    f32x4 z = {0.f, 0.f, 0.f, 0.f};
    f32x4 d1 = __builtin_amdgcn_mfma_f32_16x16x32_bf16(aprobe, bone, z, 0, 0, 0); // row+1
    f32x4 d2 = __builtin_amdgcn_mfma_f32_16x16x32_bf16(aone,  bcol, z, 0, 0, 0);  // col+1
    int R[4], Cc[4];
    #pragma unroll
    for (int r = 0; r < 4; ++r) {
        R[r]  = (int)(d1[r] + 0.5f) - 1;
        Cc[r] = (int)(d2[r] + 0.5f) - 1;
    }

    // ---------- GEMM: kqv[80][192] = x @ [wk|wq|wv], 6-term split ----------
    // A-fragment for (mt, ks): lane holds x[m0+mt*16+arow][t*64+ks*32+apart*8 .. +8]
    f32x4 acc[5][3] = {};                 // 5 m-tiles x 3 n-tiles

    for (int t = 0; t < KCHUNKS; ++t) {
        #pragma unroll
        for (int ks = 0; ks < 2; ++ks) {
            // W fragments from L2 (shared across all blocks)
            bf16x8 wfh[3], wfm[3], wfl[3];
            #pragma unroll
            for (int nt = 0; nt < 3; ++nt) {
                int n = nbase + nt * 16 + arow;
                size_t off = (size_t)n * D + t * 64 + ks * 32 + apart * 8;
                wfh[nt] = *reinterpret_cast<const bf16x8*>(wth + off);
                wfm[nt] = *reinterpret_cast<const bf16x8*>(wtm + off);
                wfl[nt] = *reinterpret_cast<const bf16x8*>(wtl + off);
            }
            #pragma unroll
            for (int mt = 0; mt < 5; ++mt) {
                const float* xp = x + (size_t)(m0 + mt * 16 + arow) * D
                                    + t * 64 + ks * 32 + apart * 8;
                f32x4 xa = *reinterpret_cast<const f32x4*>(xp);
                f32x4 xb = *reinterpret_cast<const f32x4*>(xp + 4);
                bf16x8 ah, am, al;
                #pragma unroll
                for (int e = 0; e < 8; ++e) {
                    float xe = (e < 4) ? xa[e] : xb[e - 4];
                    unsigned short h = (unsigned short)(__builtin_bit_cast(unsigned int, xe) >> 16);
                    float r1 = xe - bf2f(h);
                    unsigned short mq = (unsigned short)(__builtin_bit_cast(unsigned int, r1) >> 16);
                    float r2 = r1 - bf2f(mq);
                    ah[e] = (short)h; am[e] = (short)mq;
                    al[e] = (short)(unsigned short)(__builtin_bit_cast(unsigned int, r2) >> 16);
                }
                #pragma unroll
                for (int nt = 0; nt < 3; ++nt) {
                    acc[mt][nt] = __builtin_amdgcn_mfma_f32_16x16x32_bf16(ah, wfh[nt], acc[mt][nt], 0, 0, 0);
                    acc[mt][nt] = __builtin_amdgcn_mfma_f32_16x16x32_bf16(ah, wfm[nt], acc[mt][nt], 0, 0, 0);
                    acc[mt][nt] = __builtin_amdgcn_mfma_f32_16x16x32_bf16(am, wfh[nt], acc[mt][nt], 0, 0, 0);
                    acc[mt][nt] = __builtin_amdgcn_mfma_f32_16x16x32_bf16(ah, wfl[nt], acc[mt][nt], 0, 0, 0);
                    acc[mt][nt] = __builtin_amdgcn_mfma_f32_16x16x32_bf16(am, wfm[nt], acc[mt][nt], 0, 0, 0);
                    acc[mt][nt] = __builtin_amdgcn_mfma_f32_16x16x32_bf16(al, wfh[nt], acc[mt][nt], 0, 0, 0);
                }
            }
        }
    }

    // ---------- epilogue: two-phase (kq -> scores -> v overlay -> PV), f64 ----
    // phase 1: dump k,q columns (col < 128)
    #pragma unroll
    for (int mt = 0; mt < 5; ++mt) {
        #pragma unroll
        for (int r = 0; r < 4; ++r) {
            int row = mt * 16 + R[r];
            #pragma unroll
            for (int nt = 0; nt < 3; ++nt) {
                int colbase = nbase + nt * 16;
                if (colbase < 128)
                    kq[row * KQSTR + colbase + Cc[r]] = acc[mt][nt][r];
            }
        }
    }
    __syncthreads();

    // phase 2: masked scores for both batches of this wave (f64)
    double* sc0 = scd + wave * 220;
    #pragma unroll
    for (int bb = 0; bb < 2; ++bb) {
        const int r0 = (wave * 2 + bb) * 10;
        double* sc = sc0 + bb * 110;
        #pragma unroll
        for (int it = 0; it < 2; ++it) {
            int p = it * 64 + lane;
            if (p < 100) {
                int i = p / 10;
                int j = p - i * 10;
                double s = 0.0;
                #pragma unroll 8
                for (int c = 0; c < 64; ++c)
                    s += (double)kq[(r0 + i) * KQSTR + c] *
                         (double)kq[(r0 + j) * KQSTR + 64 + c];
                double lim = (j <= i) ? 1e5 : -1e5;
                sc[i * 11 + j] = fmin(s, lim);
            }
        }
    }
    __syncthreads();   // kq reads done -> safe to overlay v

    // phase 3: softmax (lanes 0-9) in parallel with v dump (cols >= 128)
    if (lane < 10) {
        int i = lane;
        #pragma unroll
        for (int bb = 0; bb < 2; ++bb) {
            double* sc = sc0 + bb * 110;
            double vals[10];
            double mx = -1e300;
            #pragma unroll
            for (int j = 0; j < 10; ++j) { vals[j] = sc[i * 11 + j]; mx = fmax(mx, vals[j]); }
            double sum = 0.0;
            #pragma unroll
            for (int j = 0; j < 10; ++j) { vals[j] = exp(vals[j] - mx); sum += vals[j]; }
            double inv = 1.0 / sum;
            #pragma unroll
            for (int j = 0; j < 10; ++j) sc[i * 11 + j] = vals[j] * inv;
        }
    }
    #pragma unroll
    for (int mt = 0; mt < 5; ++mt) {
        #pragma unroll
        for (int r = 0; r < 4; ++r) {
            int row = mt * 16 + R[r];
            #pragma unroll
            for (int nt = 0; nt < 3; ++nt) {
                int colbase = nbase + nt * 16;
                if (colbase >= 128)
                    vv[row * VSTR + (colbase - 128) + Cc[r]] = acc[mt][nt][r];
            }
        }
    }
    __syncthreads();

    // phase 4: PV (f64) + f32 store; lane = output column
    #pragma unroll
    for (int bb = 0; bb < 2; ++bb) {
        const int bloc = wave * 2 + bb;
        const int r0   = bloc * 10;
        double* sc = sc0 + bb * 110;
        size_t ob = (size_t)(blockIdx.x * 8 + bloc) * 640;
        #pragma unroll
        for (int i = 0; i < 10; ++i) {
            double o = 0.0;
            #pragma unroll
            for (int j = 0; j < 10; ++j)
                o += sc[i * 11 + j] * (double)vv[(r0 + j) * VSTR + lane];
            out[ob + (size_t)i * 64 + lane] = (float)o;
        }
    }
}

extern "C" void kernel_launch(void* const* d_in, const int* in_sizes, int n_in,
                              void* d_out, int out_size, void* d_ws, size_t ws_size,
                              hipStream_t stream) {
    const float* x  = (const float*)d_in[0];
    const float* wk = (const float*)d_in[1];
    const float* wq = (const float*)d_in[2];
    const float* wv = (const float*)d_in[3];
    unsigned short* wth = (unsigned short*)d_ws;          // 3 x 192*1024 bf16
    unsigned short* wtm = wth + 192 * 1024;
    unsigned short* wtl = wtm + 192 * 1024;
    float* outp = (float*)d_out;                          // FLOAT32 output

    prep_w<<<768, 256, 0, stream>>>(wk, wq, wv, wth, wtm, wtl);
    fused_attn<<<2048, 256, 0, stream>>>(x, wth, wtm, wtl, outp);
}

// Round 10
// 404.185 us; speedup vs baseline: 1.5051x; 1.5051x over previous
//
#include <hip/hip_runtime.h>

// AttentionHead: B=16384, W=10, D=1024, K=V=64
// out[b,i,:] = softmax_j( min(k_i . q_j, tri) ) @ v    (scores row = key index)
//
// GEMM front-end: 6-term split-bf16 MFMA (x,w in 3 bf16 pieces; products
// hh,hm,mh,hl,mm,lh) -> fp32-grade projections; f64-dot attention epilogue;
// FLOAT32 output.
//
// Round-10: R7's single-buffered LDS staging (convert once, read 4x) +
// R8's issue-early x prefetch + R9's compact two-phase epilogue ->
// LDS 45 KB -> 3 blocks/CU (12 waves) to cover barrier drains / L2 latency.

#define D 1024
#define BM 80            // 8 batches of 10 rows per block
#define KCHUNKS 16       // 1024 / 64
#define ASTR 72          // staged row stride in shorts (64 data + 8 pad)
#define APIECE 11520     // bytes per staged piece [80][ASTR]
#define KQSTR 133        // kq row stride (floats)
#define VSTR 65          // v row stride (floats), overlay
#define SCOFF 42560      // byte offset of score buffer
#define SMEMSZ 46080     // 42560 + 4*220*4

typedef __attribute__((ext_vector_type(8))) short bf16x8;
typedef __attribute__((ext_vector_type(4))) float f32x4;
typedef __attribute__((ext_vector_type(4))) unsigned short u16x4;

static __device__ __forceinline__ unsigned short f2bf_rtne(float f) {
    unsigned int u = __builtin_bit_cast(unsigned int, f);
    u += 0x7fffu + ((u >> 16) & 1u);
    return (unsigned short)(u >> 16);
}
static __device__ __forceinline__ float bf2f(unsigned short h) {
    unsigned int u = ((unsigned int)h) << 16;
    return __builtin_bit_cast(float, u);
}

// --- kernel0: split wk|wq|wv into transposed bf16 3-piece Wt[n][k]
__global__ __launch_bounds__(256) void prep_w(const float* __restrict__ wk,
                                              const float* __restrict__ wq,
                                              const float* __restrict__ wv,
                                              unsigned short* __restrict__ wth,
                                              unsigned short* __restrict__ wtm,
                                              unsigned short* __restrict__ wtl) {
    int idx = blockIdx.x * 256 + threadIdx.x;   // idx = n*1024 + kk, n in [0,192)
    int n  = idx >> 10;
    int kk = idx & 1023;
    const float* src = (n < 64) ? wk : (n < 128) ? wq : wv;
    float w = src[kk * 64 + (n & 63)];
    unsigned short h = f2bf_rtne(w);
    float r1 = w - bf2f(h);                     // exact
    unsigned short m = f2bf_rtne(r1);
    float r2 = r1 - bf2f(m);                    // exact
    wth[idx] = h;
    wtm[idx] = m;
    wtl[idx] = f2bf_rtne(r2);
}

// --- kernel1: fused 6-term projection GEMM + attention
__global__ __launch_bounds__(256, 3) void fused_attn(
        const float* __restrict__ x,
        const unsigned short* __restrict__ wth,
        const unsigned short* __restrict__ wtm,
        const unsigned short* __restrict__ wtl,
        float* __restrict__ out) {

    __shared__ char smem[SMEMSZ];
    // staging view: 3 pieces [80][ASTR] bf16
    unsigned short* AhS = (unsigned short*)smem;
    unsigned short* AmS = (unsigned short*)(smem + APIECE);
    unsigned short* AlS = (unsigned short*)(smem + 2 * APIECE);
    // epilogue view
    float* kq  = (float*)smem;                   // [80][KQSTR] = 42560 B
    float* vv  = (float*)smem;                   // [80][VSTR] overlay
    float* scw = (float*)(smem + SCOFF);         // [4][220] f32 probs

    const int tid  = threadIdx.x;
    const int wave = tid >> 6;
    const int lane = tid & 63;
    const int m0   = blockIdx.x * BM;
    const int nbase = wave * 48;          // 3 n-tiles of 16 per wave (192 total)
    const int arow  = lane & 15;
    const int apart = lane >> 4;          // 0..3

    // ---------- layout probe (register-only): acc (lane,reg) -> (row, col) ----
    bf16x8 aprobe = {}, bone = {}, aone = {}, bcol = {};
    if (apart == 0) {
        aprobe[0] = (short)f2bf_rtne((float)(arow + 1));  // A[m][0] = m+1
        bone[0]   = (short)0x3F80;                        // B[0][n] = 1
        aone[0]   = (short)0x3F80;                        // A[m][0] = 1
        bcol[0]   = (short)f2bf_rtne((float)(arow + 1));  // B[0][n] = n+1
    }
    f32x4 z = {0.f, 0.f, 0.f, 0.f};
    f32x4 d1 = __builtin_amdgcn_mfma_f32_16x16x32_bf16(aprobe, bone, z, 0, 0, 0); // row+1
    f32x4 d2 = __builtin_amdgcn_mfma_f32_16x16x32_bf16(aone,  bcol, z, 0, 0, 0);  // col+1
    int R[4], Cc[4];
    #pragma unroll
    for (int r = 0; r < 4; ++r) {
        R[r]  = (int)(d1[r] + 0.5f) - 1;
        Cc[r] = (int)(d2[r] + 0.5f) - 1;
    }

    // per-thread staging coords (p = tid + it*256 -> row, col)
    int srow[5], scol[5];
    #pragma unroll
    for (int it = 0; it < 5; ++it) {
        int p = tid + it * 256;
        srow[it] = p >> 4;
        scol[it] = (p & 15) << 2;
    }

    // ---------- GEMM: kqv[80][192] = x @ [wk|wq|wv], 6-term split ----------
    f32x4 acc[5][3] = {};                 // 5 m-tiles x 3 n-tiles

    // helper lambda-free staging: convert xv -> 3 pieces and write LDS
    // (done inline twice: prologue + loop)

    // prologue: stage chunk 0
    {
        float4 xv[5];
        #pragma unroll
        for (int it = 0; it < 5; ++it)
            xv[it] = *reinterpret_cast<const float4*>(
                x + (size_t)(m0 + srow[it]) * D + scol[it]);
        #pragma unroll
        for (int it = 0; it < 5; ++it) {
            u16x4 hh, mm, ll;
            #pragma unroll
            for (int e = 0; e < 4; ++e) {
                float xe = (e == 0) ? xv[it].x : (e == 1) ? xv[it].y : (e == 2) ? xv[it].z : xv[it].w;
                unsigned short h = (unsigned short)(__builtin_bit_cast(unsigned int, xe) >> 16);
                float r1 = xe - bf2f(h);
                unsigned short mq = (unsigned short)(__builtin_bit_cast(unsigned int, r1) >> 16);
                float r2 = r1 - bf2f(mq);
                hh[e] = h; mm[e] = mq;
                ll[e] = (unsigned short)(__builtin_bit_cast(unsigned int, r2) >> 16);
            }
            int ro = srow[it] * ASTR + scol[it];
            *reinterpret_cast<u16x4*>(AhS + ro) = hh;
            *reinterpret_cast<u16x4*>(AmS + ro) = mm;
            *reinterpret_cast<u16x4*>(AlS + ro) = ll;
        }
    }
    __syncthreads();

    for (int t = 0; t < KCHUNKS; ++t) {
        // issue next chunk's x loads EARLY (latency hides under MFMA phase)
        float4 xv[5];
        if (t < KCHUNKS - 1) {
            #pragma unroll
            for (int it = 0; it < 5; ++it)
                xv[it] = *reinterpret_cast<const float4*>(
                    x + (size_t)(m0 + srow[it]) * D + (t + 1) * 64 + scol[it]);
        }

        // MFMA phase on staged chunk t
        #pragma unroll
        for (int ks = 0; ks < 2; ++ks) {
            bf16x8 wfh[3], wfm[3], wfl[3];
            #pragma unroll
            for (int nt = 0; nt < 3; ++nt) {
                int n = nbase + nt * 16 + arow;
                size_t off = (size_t)n * D + t * 64 + ks * 32 + apart * 8;
                wfh[nt] = *reinterpret_cast<const bf16x8*>(wth + off);
                wfm[nt] = *reinterpret_cast<const bf16x8*>(wtm + off);
                wfl[nt] = *reinterpret_cast<const bf16x8*>(wtl + off);
            }
            #pragma unroll
            for (int mt = 0; mt < 5; ++mt) {
                int ab = (mt * 16 + arow) * (ASTR * 2) + (ks * 4 + apart) * 16;
                bf16x8 ah = *reinterpret_cast<const bf16x8*>((char*)AhS + ab);
                bf16x8 am = *reinterpret_cast<const bf16x8*>((char*)AmS + ab);
                bf16x8 al = *reinterpret_cast<const bf16x8*>((char*)AlS + ab);
                #pragma unroll
                for (int nt = 0; nt < 3; ++nt) {
                    acc[mt][nt] = __builtin_amdgcn_mfma_f32_16x16x32_bf16(ah, wfh[nt], acc[mt][nt], 0, 0, 0);
                    acc[mt][nt] = __builtin_amdgcn_mfma_f32_16x16x32_bf16(ah, wfm[nt], acc[mt][nt], 0, 0, 0);
                    acc[mt][nt] = __builtin_amdgcn_mfma_f32_16x16x32_bf16(am, wfh[nt], acc[mt][nt], 0, 0, 0);
                    acc[mt][nt] = __builtin_amdgcn_mfma_f32_16x16x32_bf16(ah, wfl[nt], acc[mt][nt], 0, 0, 0);
                    acc[mt][nt] = __builtin_amdgcn_mfma_f32_16x16x32_bf16(am, wfm[nt], acc[mt][nt], 0, 0, 0);
                    acc[mt][nt] = __builtin_amdgcn_mfma_f32_16x16x32_bf16(al, wfh[nt], acc[mt][nt], 0, 0, 0);
                }
            }
        }
        __syncthreads();          // all reads of the staging buffer done

        if (t < KCHUNKS - 1) {
            #pragma unroll
            for (int it = 0; it < 5; ++it) {
                u16x4 hh, mm, ll;
                #pragma unroll
                for (int e = 0; e < 4; ++e) {
                    float xe = (e == 0) ? xv[it].x : (e == 1) ? xv[it].y : (e == 2) ? xv[it].z : xv[it].w;
                    unsigned short h = (unsigned short)(__builtin_bit_cast(unsigned int, xe) >> 16);
                    float r1 = xe - bf2f(h);
                    unsigned short mq = (unsigned short)(__builtin_bit_cast(unsigned int, r1) >> 16);
                    float r2 = r1 - bf2f(mq);
                    hh[e] = h; mm[e] = mq;
                    ll[e] = (unsigned short)(__builtin_bit_cast(unsigned int, r2) >> 16);
                }
                int ro = srow[it] * ASTR + scol[it];
                *reinterpret_cast<u16x4*>(AhS + ro) = hh;
                *reinterpret_cast<u16x4*>(AmS + ro) = mm;
                *reinterpret_cast<u16x4*>(AlS + ro) = ll;
            }
            __syncthreads();      // staging buffer ready for chunk t+1
        }
    }

    // ---------- epilogue: two-phase (kq -> scores -> v overlay -> PV) ----------
    // phase 1: dump k,q columns (col < 128)
    #pragma unroll
    for (int mt = 0; mt < 5; ++mt) {
        #pragma unroll
        for (int r = 0; r < 4; ++r) {
            int row = mt * 16 + R[r];
            #pragma unroll
            for (int nt = 0; nt < 3; ++nt) {
                int colbase = nbase + nt * 16;
                if (colbase < 128)
                    kq[row * KQSTR + colbase + Cc[r]] = acc[mt][nt][r];
            }
        }
    }
    __syncthreads();

    // phase 2: masked scores for both batches of this wave (f64 dots, f32 store)
    float* sc0 = scw + wave * 220;
    #pragma unroll
    for (int bb = 0; bb < 2; ++bb) {
        const int r0 = (wave * 2 + bb) * 10;
        float* sc = sc0 + bb * 110;
        #pragma unroll
        for (int it = 0; it < 2; ++it) {
            int p = it * 64 + lane;
            if (p < 100) {
                int i = p / 10;
                int j = p - i * 10;
                double s = 0.0;
                #pragma unroll 8
                for (int c = 0; c < 64; ++c)
                    s += (double)kq[(r0 + i) * KQSTR + c] *
                         (double)kq[(r0 + j) * KQSTR + 64 + c];
                double lim = (j <= i) ? 1e5 : -1e5;
                sc[i * 11 + j] = (float)fmin(s, lim);
            }
        }
    }
    __syncthreads();   // kq reads done -> safe to overlay v

    // phase 3: softmax (lanes 0-9, f64 from f32 scores) + v dump (cols >= 128)
    if (lane < 10) {
        int i = lane;
        #pragma unroll
        for (int bb = 0; bb < 2; ++bb) {
            float* sc = sc0 + bb * 110;
            double vals[10];
            double mx = -1e300;
            #pragma unroll
            for (int j = 0; j < 10; ++j) { vals[j] = (double)sc[i * 11 + j]; mx = fmax(mx, vals[j]); }
            double sum = 0.0;
            #pragma unroll
            for (int j = 0; j < 10; ++j) { vals[j] = exp(vals[j] - mx); sum += vals[j]; }
            double inv = 1.0 / sum;
            #pragma unroll
            for (int j = 0; j < 10; ++j) sc[i * 11 + j] = (float)(vals[j] * inv);
        }
    }
    #pragma unroll
    for (int mt = 0; mt < 5; ++mt) {
        #pragma unroll
        for (int r = 0; r < 4; ++r) {
            int row = mt * 16 + R[r];
            #pragma unroll
            for (int nt = 0; nt < 3; ++nt) {
                int colbase = nbase + nt * 16;
                if (colbase >= 128)
                    vv[row * VSTR + (colbase - 128) + Cc[r]] = acc[mt][nt][r];
            }
        }
    }
    __syncthreads();

    // phase 4: PV (f64 accum, f32 probs/v) + f32 store; lane = output column
    #pragma unroll
    for (int bb = 0; bb < 2; ++bb) {
        const int bloc = wave * 2 + bb;
        const int r0   = bloc * 10;
        float* sc = sc0 + bb * 110;
        size_t ob = (size_t)(blockIdx.x * 8 + bloc) * 640;
        #pragma unroll
        for (int i = 0; i < 10; ++i) {
            double o = 0.0;
            #pragma unroll
            for (int j = 0; j < 10; ++j)
                o += (double)sc[i * 11 + j] * (double)vv[(r0 + j) * VSTR + lane];
            out[ob + (size_t)i * 64 + lane] = (float)o;
        }
    }
}

extern "C" void kernel_launch(void* const* d_in, const int* in_sizes, int n_in,
                              void* d_out, int out_size, void* d_ws, size_t ws_size,
                              hipStream_t stream) {
    const float* x  = (const float*)d_in[0];
    const float* wk = (const float*)d_in[1];
    const float* wq = (const float*)d_in[2];
    const float* wv = (const float*)d_in[3];
    unsigned short* wth = (unsigned short*)d_ws;          // 3 x 192*1024 bf16
    unsigned short* wtm = wth + 192 * 1024;
    unsigned short* wtl = wtm + 192 * 1024;
    float* outp = (float*)d_out;                          // FLOAT32 output

    prep_w<<<768, 256, 0, stream>>>(wk, wq, wv, wth, wtm, wtl);
    fused_attn<<<2048, 256, 0, stream>>>(x, wth, wtm, wtl, outp);
}